// Round 3
// baseline (362.755 us; speedup 1.0000x reference)
//
#include <hip/hip_runtime.h>

typedef unsigned short u16;
typedef __attribute__((ext_vector_type(8))) short v8s;   // 8 x bf16 (4 VGPRs)
typedef __attribute__((ext_vector_type(4))) float v4f;   // MFMA 16x16 accumulator

#define S_LEN  2048
#define NHEADS 16
#define DHEAD  64
#define EMB    1024

#if __has_builtin(__builtin_amdgcn_exp2f)
#define EXP2F __builtin_amdgcn_exp2f
#else
#define EXP2F exp2f
#endif

__device__ __forceinline__ u16 f32_bf16(float f) {
  union { float f; unsigned u; } x; x.f = f;
  unsigned r = x.u + 0x7fffu + ((x.u >> 16) & 1u);   // RNE
  return (u16)(r >> 16);
}

__device__ __forceinline__ void async16(const void* g, void* l) {
  // global -> LDS direct DMA, 16B per lane; LDS dest = wave-uniform base + lane*16
  __builtin_amdgcn_global_load_lds(
      (const __attribute__((address_space(1))) unsigned int*)g,
      (__attribute__((address_space(3))) unsigned int*)l, 16, 0, 0);
}

#define FENCE() asm volatile("" ::: "memory")

// ---- fp32 -> bf16 conversion, all 7 tensors in one launch ----
__global__ __launch_bounds__(256) void cvt_all(
    const float4* __restrict__ s0, const float4* __restrict__ s1,
    const float4* __restrict__ s2, const float4* __restrict__ s3,
    const float4* __restrict__ s4, const float4* __restrict__ s5,
    const float4* __restrict__ s6,
    ushort4* __restrict__ d0, ushort4* __restrict__ d1,
    ushort4* __restrict__ d2, ushort4* __restrict__ d3,
    ushort4* __restrict__ d4, ushort4* __restrict__ d5,
    ushort4* __restrict__ d6, int nbig, int nsmall) {
  const int y = blockIdx.y;
  const float4* s; ushort4* d;
  switch (y) {
    case 0: s = s0; d = d0; break;  case 1: s = s1; d = d1; break;
    case 2: s = s2; d = d2; break;  case 3: s = s3; d = d3; break;
    case 4: s = s4; d = d4; break;  case 5: s = s5; d = d5; break;
    default: s = s6; d = d6; break;
  }
  const int n4 = (y < 3) ? nbig : nsmall;
  for (int i = blockIdx.x * 256 + threadIdx.x; i < n4; i += gridDim.x * 256) {
    const float4 v = s[i];
    ushort4 o;
    o.x = f32_bf16(v.x); o.y = f32_bf16(v.y);
    o.z = f32_bf16(v.z); o.w = f32_bf16(v.w);
    d[i] = o;
  }
}

// ============================================================================
// 128x128 tile, BK=32, 4 waves (2Mx2N, 64x64/wave), TRIPLE-buffered LDS
// (3 x 8KB x 2 = 48 KB -> 3 blocks/CU), T4 counted-vmcnt pipeline:
//   iter t: [s_waitcnt vmcnt(4)] [s_barrier] [stage tile t+2 -> buf (t+2)%3]
//           [8 x ds_read_b128 from buf t%3] [16 MFMA]
// Loads for tile t get ~2 full iterations of latency budget; vmcnt never
// drains to 0 in the main loop (only the peeled last iteration waits 0).
// Race-freedom: stage(t+2) targets buf (t-1)%3; its readers (iter t-1)
// retired their ds_reads before barrier t (lgkmcnt consumed in-phase), and
// s_barrier orders every wave's stage after every wave's reads.
//
// LDS layout (packed lines): a 128x32 bf16 tile is stored as 64 lines x
// 128B; line L, slot p (16B) holds global (row = L + 64*(p>>2),
// k-chunk = p&3), stored at slot p ^ (L&7).  2-way bank aliasing on
// ds_read_b128 (free, m136); staged via pre-swizzled global source with
// linear LDS dest (global_load_lds writes base + lane*16).
//
// Block mapping (L2 supertile): XCD = bid&7 owns m-tiles [x*mt/8, ...),
// n innermost -> each A-tile is read by 8 consecutive blocks (L2-hot),
// W panels stay resident; A fetched ~once from HBM/L3.
//
// MODE 0: fused QKV projection. A=[xq;xk;xv] [24576,1024]; sec=m0>>13 picks
//         W and output (Cq/Ck: [B,H,S,D] bf16; Cv: [B,H,D,S] bf16).
// MODE 1: output projection, C fp32 row-major [M,1024].
// ============================================================================
template <int MODE>
__global__ __launch_bounds__(256, 3) void gemm3b(
    const u16* __restrict__ A, const u16* __restrict__ W0,
    const u16* __restrict__ W1, const u16* __restrict__ W2,
    u16* __restrict__ Cq, u16* __restrict__ Ck, u16* __restrict__ Cv,
    float* __restrict__ Cf, int mtiles) {
  const int K = 1024;
  const int NKT = 32;                            // K / 32
  __shared__ __align__(16) u16 lA[3][4096];      // 3 x 8 KB
  __shared__ __align__(16) u16 lB[3][4096];      // total 48 KB
  const int t = threadIdx.x;
  const int lane = t & 63, wv = t >> 6;
  const int wm = wv >> 1, wn = wv & 1;           // 2M x 2N waves, 64x64/wave
  const int qr = lane >> 4, cl = lane & 15;

  // L2 supertile: XCD owns an m-chunk, n innermost
  const int xcd = blockIdx.x & 7, q = blockIdx.x >> 3;
  const int mt = xcd * (mtiles >> 3) + (q >> 3), nt = q & 7;
  const int m0 = mt << 7, n0 = nt << 7;
  const int sec = (MODE == 0) ? (m0 >> 13) : 0;
  const u16* W =
      (MODE == 0) ? ((sec == 0) ? W0 : (sec == 1) ? W1 : W2) : W0;

  v4f acc[4][4];
#pragma unroll
  for (int i = 0; i < 4; ++i)
#pragma unroll
    for (int j = 0; j < 4; ++j) acc[i][j] = (v4f){0.f, 0.f, 0.f, 0.f};

  // ---- staging source precompute (packed-line swizzle, see header) ----
  const int Lt = t >> 3;                 // dest line (unit 0)
  const int pt = (t & 7) ^ (Lt & 7);     // logical slot
  const int rh = (pt >> 2) << 6;         // row-half: 0 or 64
  const int kc8 = (pt & 3) << 3;         // k-chunk offset in elems
  const u16* aS[2];
  const u16* bS[2];
#pragma unroll
  for (int u = 0; u < 2; ++u) {
    aS[u] = A + (size_t)(m0 + Lt + u * 32 + rh) * K + kc8;
    bS[u] = W + (size_t)(n0 + Lt + u * 32 + rh) * K + kc8;
  }
  u16* const lA0 = &lA[0][0];
  u16* const lB0 = &lB[0][0];

  // ---- read offsets (u16 units): row R, k-quarter qr ----
  int aOff[4], bOff[4];
#pragma unroll
  for (int f = 0; f < 4; ++f) {
    aOff[f] = (f * 16 + cl) * 64 + ((((wm << 2) | qr) ^ (cl & 7)) << 3);
    bOff[f] = (f * 16 + cl) * 64 + ((((wn << 2) | qr) ^ (cl & 7)) << 3);
  }

#define STAGE3(TILE, BUF)                                                     \
  do {                                                                        \
    const int ka_ = (TILE) << 5;                                              \
    u16* da_ = lA0 + (BUF) * 4096;                                            \
    u16* db_ = lB0 + (BUF) * 4096;                                            \
    async16(aS[0] + ka_, da_ + t * 8);                                        \
    async16(aS[1] + ka_, da_ + (t + 256) * 8);                                \
    async16(bS[0] + ka_, db_ + t * 8);                                        \
    async16(bS[1] + ka_, db_ + (t + 256) * 8);                                \
  } while (0)

#define BODY3(CUR)                                                            \
  do {                                                                        \
    const u16* ra_ = lA0 + (CUR) * 4096;                                      \
    const u16* rb_ = lB0 + (CUR) * 4096;                                      \
    v8s a_[4], b_[4];                                                         \
    _Pragma("unroll") for (int mf = 0; mf < 4; ++mf)                          \
        a_[mf] = *(const v8s*)(ra_ + aOff[mf]);                               \
    _Pragma("unroll") for (int nf = 0; nf < 4; ++nf)                          \
        b_[nf] = *(const v8s*)(rb_ + bOff[nf]);                               \
    __builtin_amdgcn_s_setprio(1);                                            \
    _Pragma("unroll") for (int mf = 0; mf < 4; ++mf)                          \
        _Pragma("unroll") for (int nf = 0; nf < 4; ++nf)                      \
            acc[mf][nf] = __builtin_amdgcn_mfma_f32_16x16x32_bf16(            \
                a_[mf], b_[nf], acc[mf][nf], 0, 0, 0);                        \
    __builtin_amdgcn_s_setprio(0);                                            \
  } while (0)

  // prologue: tiles 0,1 in flight (8 loads)
  STAGE3(0, 0);
  STAGE3(1, 1);
  FENCE();

  int cur = 0, stg = 2;
  for (int kt = 0; kt < NKT - 1; ++kt) {
    asm volatile("s_waitcnt vmcnt(4)" ::: "memory");   // tile kt landed
    FENCE();
    __builtin_amdgcn_s_barrier();
    FENCE();
    if (kt < NKT - 2) STAGE3(kt + 2, stg);
    BODY3(cur);
    cur = (cur == 2) ? 0 : cur + 1;
    stg = (stg == 2) ? 0 : stg + 1;
  }
  // peeled last iteration: full drain (only place vmcnt reaches 0)
  asm volatile("s_waitcnt vmcnt(0)" ::: "memory");
  FENCE();
  __builtin_amdgcn_s_barrier();
  FENCE();
  BODY3(cur);

#undef STAGE3
#undef BODY3

  // ---- epilogue ----
  if constexpr (MODE == 0) {
    u16* C = (sec == 0) ? Cq : (sec == 1) ? Ck : Cv;
#pragma unroll
    for (int mf = 0; mf < 4; ++mf)
#pragma unroll
      for (int nf = 0; nf < 4; ++nf)
#pragma unroll
        for (int r = 0; r < 4; ++r) {
          const int mloc = (m0 & 8191) + wm * 64 + mf * 16 + qr * 4 + r;
          const int n = n0 + wn * 64 + nf * 16 + cl;
          const int bb = mloc >> 11, s = mloc & (S_LEN - 1);
          const int h = n >> 6, d = n & (DHEAD - 1);
          const size_t idx =
              (sec < 2) ? (((size_t)bb * NHEADS + h) * S_LEN + s) * DHEAD + d
                        : (((size_t)bb * NHEADS + h) * DHEAD + d) * S_LEN + s;
          C[idx] = f32_bf16(acc[mf][nf][r]);
        }
  } else {
#pragma unroll
    for (int mf = 0; mf < 4; ++mf)
#pragma unroll
      for (int nf = 0; nf < 4; ++nf)
#pragma unroll
        for (int r = 0; r < 4; ++r) {
          const int m = m0 + wm * 64 + mf * 16 + qr * 4 + r;
          const int n = n0 + wn * 64 + nf * 16 + cl;
          Cf[(size_t)m * 1024 + n] = acc[mf][nf][r];
        }
  }
}

// Causal flash attention, no-max softmax. Qp/Kp: [B,H,S,D]; VpT: [B,H,D,S].
// 512 blocks; block = (column, pair): processes q-tile 15-pair then pair ->
// exactly 34 K-iterations per block (perfect causal load balance).
// Single-barrier double-buffered K-loop; XCD-swizzled (8 columns per XCD).
__global__ __launch_bounds__(256) void attn_causal(const u16* __restrict__ Qp,
                                                   const u16* __restrict__ Kp,
                                                   const u16* __restrict__ VpT,
                                                   u16* __restrict__ Out) {
  __shared__ __align__(16) u16 lK[2][64 * 64];  // chunk(key,dc)=key*8+(dc^(key&7))
  __shared__ __align__(16) u16 lV[2][64 * 64];  // chunk(d,kc)=d*8+(kc^(d&7))
  __shared__ __align__(16) u16 pb[4][32 * 64];  // per-wave P: chunk=kc*32+sig(row)
  const int t = threadIdx.x;
  const int lane = t & 63, w = t >> 6;
  const int qr = lane >> 4, cl = lane & 15;
  // id = xcd + 8*(pair + 8*colgroup): all 8 pairs of 8 columns share an XCD
  const int id = blockIdx.x;
  const int col = (id & 7) + ((id >> 6) << 3);   // 0..63 = h + 16*b
  const int pair = (id >> 3) & 7;
  const int h = col & 15, b = col >> 4;
  const size_t bh = ((size_t)b * NHEADS + h) * S_LEN * DHEAD;
  const u16* Qb = Qp + bh;
  const u16* Kb = Kp + bh;
  const u16* Vb = VpT + bh;   // [d][s], row stride S_LEN

  v8s vone;
#pragma unroll
  for (int j = 0; j < 8; ++j) vone[j] = (short)0x3F80;   // bf16 1.0
  const float SC = 0.125f * 1.4426950408889634f;         // (1/8)*log2(e)

  for (int phase = 0; phase < 2; ++phase) {
    const int qt = phase == 0 ? (15 - pair) : pair;   // heavy tile first
    const int q0 = qt << 7;
    const int wr0 = q0 + w * 32;   // this wave's first q-row

    v8s aq[2][2];
#pragma unroll
    for (int mf = 0; mf < 2; ++mf)
#pragma unroll
      for (int kf = 0; kf < 2; ++kf)
        aq[mf][kf] = *(const v8s*)(Qb + (size_t)(wr0 + mf * 16 + cl) * DHEAD +
                                   kf * 32 + qr * 8);

    v4f o[2][4], lac[2];
#pragma unroll
    for (int mf = 0; mf < 2; ++mf) {
      lac[mf] = (v4f){0.f, 0.f, 0.f, 0.f};
#pragma unroll
      for (int nf = 0; nf < 4; ++nf) o[mf][nf] = (v4f){0.f, 0.f, 0.f, 0.f};
    }

    const int nkt = 2 * qt + 2;
    __syncthreads();   // prior phase's LDS reads complete before re-staging
    // prologue: stage tile 0 into buffer 0
#pragma unroll
    for (int i = 0; i < 2; ++i) {
      const int c = t + (i << 8);
      const int krow = c >> 3, kdc = (c & 7) ^ (krow & 7);
      async16(Kb + (size_t)krow * DHEAD + kdc * 8, &lK[0][(w * 64 + (i << 8)) * 8]);
      const int vd = c >> 3, vkc = (c & 7) ^ (vd & 7);
      async16(Vb + (size_t)vd * S_LEN + vkc * 8, &lV[0][(w * 64 + (i << 8)) * 8]);
    }

    for (int kt = 0; kt < nkt; ++kt) {
      const int k0 = kt << 6;
      const int cb = kt & 1;
      __syncthreads();   // stage(kt) visible in buf cb; buf 1-cb free
      if (kt + 1 < nkt) {
        const int kn = (kt + 1) << 6;
#pragma unroll
        for (int i = 0; i < 2; ++i) {
          const int c = t + (i << 8);
          const int krow = c >> 3, kdc = (c & 7) ^ (krow & 7);
          async16(Kb + (size_t)(kn + krow) * DHEAD + kdc * 8,
                  &lK[1 - cb][(w * 64 + (i << 8)) * 8]);
          const int vd = c >> 3, vkc = (c & 7) ^ (vd & 7);
          async16(Vb + (size_t)vd * S_LEN + kn + vkc * 8,
                  &lV[1 - cb][(w * 64 + (i << 8)) * 8]);
        }
      }
      if (k0 > wr0 + 31) continue;   // wave-uniform: tile fully above diagonal

      // ---- S = Q K^T  (16 MFMA) ----
      v4f sacc[2][4];
#pragma unroll
      for (int mf = 0; mf < 2; ++mf)
#pragma unroll
        for (int ni = 0; ni < 4; ++ni) sacc[mf][ni] = (v4f){0.f, 0.f, 0.f, 0.f};
#pragma unroll
      for (int kf = 0; kf < 2; ++kf)
#pragma unroll
        for (int ni = 0; ni < 4; ++ni) {
          const v8s bk = *(const v8s*)&lK[cb][((ni * 16 + cl) * 8 +
                                              (((kf << 2) + qr) ^ (cl & 7))) * 8];
          sacc[0][ni] = __builtin_amdgcn_mfma_f32_16x16x32_bf16(aq[0][kf], bk,
                                                                sacc[0][ni], 0, 0, 0);
          sacc[1][ni] = __builtin_amdgcn_mfma_f32_16x16x32_bf16(aq[1][kf], bk,
                                                                sacc[1][ni], 0, 0, 0);
        }

      // ---- exp2, (diagonal-only) mask, truncate-to-bf16, store P ----
#pragma unroll
      for (int mf = 0; mf < 2; ++mf) {
        const int rowb0 = wr0 + mf * 16;
        if (k0 + 63 <= rowb0) {        // wave-uniform: no masking on this frag
#pragma unroll
          for (int ni = 0; ni < 4; ++ni) {
            const int kc = ni * 2 + (cl >> 3);
#pragma unroll
            for (int r = 0; r < 4; ++r) {
              const float e = EXP2F(sacc[mf][ni][r] * SC);
              pb[w][((kc * 32 + mf * 16 + r * 4 + qr) << 3) + (cl & 7)] =
                  (u16)(__float_as_uint(e) >> 16);
            }
          }
        } else {                        // diagonal: mask then exp
          const int rowb = rowb0 + qr * 4;
#pragma unroll
          for (int ni = 0; ni < 4; ++ni) {
            const int colk = k0 + ni * 16 + cl;
            const int kc = ni * 2 + (cl >> 3);
#pragma unroll
            for (int r = 0; r < 4; ++r) {
              float e = EXP2F(sacc[mf][ni][r] * SC);
              if (colk > rowb + r) e = 0.f;
              pb[w][((kc * 32 + mf * 16 + r * 4 + qr) << 3) + (cl & 7)] =
                  (u16)(__float_as_uint(e) >> 16);
            }
          }
        }
      }

      // ---- O += P V, l += P 1  (wave-local pb: lgkmcnt ordering only) ----
#pragma unroll
      for (int kf = 0; kf < 2; ++kf) {
        const int kc = (kf << 2) + qr;
        const int sig0 = ((cl & 3) << 2) + (cl >> 2);
        const v8s ap0 = *(const v8s*)&pb[w][((kc * 32 + sig0) << 3)];
        const v8s ap1 = *(const v8s*)&pb[w][((kc * 32 + 16 + sig0) << 3)];
        lac[0] = __builtin_amdgcn_mfma_f32_16x16x32_bf16(ap0, vone, lac[0], 0, 0, 0);
        lac[1] = __builtin_amdgcn_mfma_f32_16x16x32_bf16(ap1, vone, lac[1], 0, 0, 0);
#pragma unroll
        for (int nf = 0; nf < 4; ++nf) {
          const v8s bv = *(const v8s*)&lV[cb][((nf * 16 + cl) * 8 +
                                              (kc ^ (cl & 7))) * 8];
          o[0][nf] = __builtin_amdgcn_mfma_f32_16x16x32_bf16(ap0, bv, o[0][nf], 0, 0, 0);
          o[1][nf] = __builtin_amdgcn_mfma_f32_16x16x32_bf16(ap1, bv, o[1][nf], 0, 0, 0);
        }
      }
    }

    // epilogue: O / l
#pragma unroll
    for (int mf = 0; mf < 2; ++mf) {
      float inv[4];
#pragma unroll
      for (int r = 0; r < 4; ++r) inv[r] = 1.0f / lac[mf][r];
#pragma unroll
      for (int nf = 0; nf < 4; ++nf)
#pragma unroll
        for (int r = 0; r < 4; ++r) {
          const int row = wr0 + mf * 16 + qr * 4 + r;
          const int colo = h * DHEAD + nf * 16 + cl;
          Out[((size_t)b * S_LEN + row) * EMB + colo] = f32_bf16(o[mf][nf][r] * inv[r]);
        }
    }
  }
}

extern "C" void kernel_launch(void* const* d_in, const int* in_sizes, int n_in,
                              void* d_out, int out_size, void* d_ws, size_t ws_size,
                              hipStream_t stream) {
  (void)in_sizes; (void)n_in; (void)out_size; (void)ws_size;
  const float* q  = (const float*)d_in[0];
  const float* k  = (const float*)d_in[1];
  const float* v  = (const float*)d_in[2];
  // d_in[3] = causal mask (int32) — implemented analytically, not read
  const float* wq = (const float*)d_in[4];
  const float* wk = (const float*)d_in[5];
  const float* wv = (const float*)d_in[6];
  const float* wo = (const float*)d_in[7];
  float* out = (float*)d_out;   // reference output dtype is float32

  const size_t MT = (size_t)4 * S_LEN * EMB;   // 8,388,608 elems
  const size_t WT = (size_t)EMB * EMB;         // 1,048,576 elems
  u16* p = (u16*)d_ws;
  u16* xq = p; p += MT;     // xq|xk|xv contiguous: A-matrix of the fused QKV GEMM
  u16* xk = p; p += MT;
  u16* xv = p; p += MT;
  u16* wqb = p; p += WT;
  u16* wkb = p; p += WT;
  u16* wvb = p; p += WT;
  u16* wob = p; p += WT;
  u16* Qp = p; p += MT;
  u16* Kp = p; p += MT;
  u16* Vp = p; p += MT;
  u16* Ao = xq;          // xq dead after projection GEMM — reuse

  const dim3 blk(256);
  hipLaunchKernelGGL(cvt_all, dim3(512, 7), blk, 0, stream,
                     (const float4*)q, (const float4*)k, (const float4*)v,
                     (const float4*)wq, (const float4*)wk, (const float4*)wv,
                     (const float4*)wo,
                     (ushort4*)xq, (ushort4*)xk, (ushort4*)xv,
                     (ushort4*)wqb, (ushort4*)wkb, (ushort4*)wvb, (ushort4*)wob,
                     (int)(MT / 4), (int)(WT / 4));
  // 192 m-tiles x 8 n-tiles = 1536 blocks; 3 blocks/CU
  hipLaunchKernelGGL((gemm3b<0>), dim3(1536), blk, 0, stream,
                     xq, wqb, wkb, wvb, Qp, Kp, Vp, (float*)nullptr, 192);
  hipLaunchKernelGGL(attn_causal, dim3(512), blk, 0, stream, Qp, Kp, Vp, Ao);
  // 64 m-tiles x 8 n-tiles = 512 blocks
  hipLaunchKernelGGL((gemm3b<1>), dim3(512), blk, 0, stream,
                     Ao, wob, (const u16*)nullptr, (const u16*)nullptr,
                     (u16*)nullptr, (u16*)nullptr, (u16*)nullptr, out, 64);
}

// Round 4
// 349.485 us; speedup vs baseline: 1.0380x; 1.0380x over previous
//
#include <hip/hip_runtime.h>

typedef unsigned short u16;
typedef __attribute__((ext_vector_type(8))) short v8s;   // 8 x bf16 (4 VGPRs)
typedef __attribute__((ext_vector_type(4))) float v4f;   // MFMA 16x16 accumulator

#define S_LEN  2048
#define NHEADS 16
#define DHEAD  64
#define EMB    1024

#if __has_builtin(__builtin_amdgcn_exp2f)
#define EXP2F __builtin_amdgcn_exp2f
#else
#define EXP2F exp2f
#endif

__device__ __forceinline__ u16 f32_bf16(float f) {
  union { float f; unsigned u; } x; x.f = f;
  unsigned r = x.u + 0x7fffu + ((x.u >> 16) & 1u);   // RNE
  return (u16)(r >> 16);
}

__device__ __forceinline__ void async16(const void* g, void* l) {
  // global -> LDS direct DMA, 16B per lane; LDS dest = wave-uniform base + lane*16
  __builtin_amdgcn_global_load_lds(
      (const __attribute__((address_space(1))) unsigned int*)g,
      (__attribute__((address_space(3))) unsigned int*)l, 16, 0, 0);
}

// ---- fp32 -> bf16 conversion, all 7 tensors in one launch ----
__global__ __launch_bounds__(256) void cvt_all(
    const float4* __restrict__ s0, const float4* __restrict__ s1,
    const float4* __restrict__ s2, const float4* __restrict__ s3,
    const float4* __restrict__ s4, const float4* __restrict__ s5,
    const float4* __restrict__ s6,
    ushort4* __restrict__ d0, ushort4* __restrict__ d1,
    ushort4* __restrict__ d2, ushort4* __restrict__ d3,
    ushort4* __restrict__ d4, ushort4* __restrict__ d5,
    ushort4* __restrict__ d6, int nbig, int nsmall) {
  const int y = blockIdx.y;
  const float4* s; ushort4* d;
  switch (y) {
    case 0: s = s0; d = d0; break;  case 1: s = s1; d = d1; break;
    case 2: s = s2; d = d2; break;  case 3: s = s3; d = d3; break;
    case 4: s = s4; d = d4; break;  case 5: s = s5; d = d5; break;
    default: s = s6; d = d6; break;
  }
  const int n4 = (y < 3) ? nbig : nsmall;
  for (int i = blockIdx.x * 256 + threadIdx.x; i < n4; i += gridDim.x * 256) {
    const float4 v = s[i];
    ushort4 o;
    o.x = f32_bf16(v.x); o.y = f32_bf16(v.y);
    o.z = f32_bf16(v.z); o.w = f32_bf16(v.w);
    d[i] = o;
  }
}

// ============================================================================
// 128x128 tile, BK=64, 4 waves (2Mx2N, 64x64/wave), 64 KiB LDS -> 2 blocks/CU.
// 2-phase K-loop (round-2 structure, best measured): stage(t+1) issued at TOP
// of the body, single __syncthreads() at bottom.
// T2 XOR-swizzle on 16B chunks within each 128B row (verified 0 conflicts).
// L2 supertile mapping (round-3, FETCH-verified 43MB): XCD owns an m-chunk,
// n innermost -> 8 consecutive blocks share each A-tile; W panel L2-resident.
//
// MODE 0: fused QKV projection. A=[xq;xk;xv] [24576,1024]; sec=m0>>13 picks
//         W and output (Cq/Ck: [B,H,S,D] bf16; Cv: [B,H,D,S] bf16).
// MODE 1: output projection, C fp32 row-major [M,1024].
// ============================================================================
template <int MODE>
__global__ __launch_bounds__(256, 2) void gemm2ph(
    const u16* __restrict__ A, const u16* __restrict__ W0,
    const u16* __restrict__ W1, const u16* __restrict__ W2,
    u16* __restrict__ Cq, u16* __restrict__ Ck, u16* __restrict__ Cv,
    float* __restrict__ Cf, int mtiles) {
  const int K = 1024;
  const int NKT = 16;                          // K / 64
  __shared__ __align__(16) u16 lA[2][128 * 64];   // 2 x 16 KB
  __shared__ __align__(16) u16 lB[2][128 * 64];   // total 64 KiB
  const int t = threadIdx.x;
  const int lane = t & 63, wv = t >> 6;
  const int wm = wv >> 1, wn = wv & 1;         // 2M x 2N wave grid, 64x64/wave
  const int qr = lane >> 4, cl = lane & 15;

  // L2 supertile: XCD owns an m-chunk, n innermost (FETCH-verified, round 3)
  const int xcd = blockIdx.x & 7, q = blockIdx.x >> 3;
  const int mt = xcd * (mtiles >> 3) + (q >> 3), nt = q & 7;
  const int m0 = mt << 7, n0 = nt << 7;
  const int sec = (MODE == 0) ? (m0 >> 13) : 0;
  const u16* W =
      (MODE == 0) ? ((sec == 0) ? W0 : (sec == 1) ? W1 : W2) : W0;

  v4f acc[4][4];
#pragma unroll
  for (int i = 0; i < 4; ++i)
#pragma unroll
    for (int j = 0; j < 4; ++j) acc[i][j] = (v4f){0.f, 0.f, 0.f, 0.f};

  // Per-thread staging source: c = t + u*256 -> row = t>>3 + u*32 (u*32 % 8 == 0
  // so the chunk swizzle is constant across u), chunk = (t&7) ^ (row&7).
  const int srow = t >> 3;
  const int sw = ((t & 7) ^ (srow & 7)) << 3;   // u16 offset within the row
  const u16* aS[4];
  const u16* bS[4];
#pragma unroll
  for (int u = 0; u < 4; ++u) {
    aS[u] = A + (size_t)(m0 + srow + u * 32) * K + sw;
    bS[u] = W + (size_t)(n0 + srow + u * 32) * K + sw;
  }

  // prologue: stage tile 0 into buf 0
#pragma unroll
  for (int u = 0; u < 4; ++u) async16(aS[u], &lA[0][(t + (u << 8)) << 3]);
#pragma unroll
  for (int u = 0; u < 4; ++u) async16(bS[u], &lB[0][(t + (u << 8)) << 3]);
  __syncthreads();

  for (int kt = 0; kt < NKT; ++kt) {
    const int cur = kt & 1;
    if (kt + 1 < NKT) {                         // stage(t+1) FIRST
      const int off = (kt + 1) << 6;
#pragma unroll
      for (int u = 0; u < 4; ++u)
        async16(aS[u] + off, &lA[1 - cur][(t + (u << 8)) << 3]);
#pragma unroll
      for (int u = 0; u < 4; ++u)
        async16(bS[u] + off, &lB[1 - cur][(t + (u << 8)) << 3]);
    }
    v8s a[4][2], b[4][2];
#pragma unroll
    for (int mf = 0; mf < 4; ++mf)
#pragma unroll
      for (int kh = 0; kh < 2; ++kh) {
        const int R = wm * 64 + mf * 16 + cl;
        a[mf][kh] =
            *(const v8s*)&lA[cur][R * 64 + ((((kh << 2) + qr) ^ (R & 7)) << 3)];
      }
#pragma unroll
    for (int nf = 0; nf < 4; ++nf)
#pragma unroll
      for (int kh = 0; kh < 2; ++kh) {
        const int R = wn * 64 + nf * 16 + cl;
        b[nf][kh] =
            *(const v8s*)&lB[cur][R * 64 + ((((kh << 2) + qr) ^ (R & 7)) << 3)];
      }
    __builtin_amdgcn_s_setprio(1);
#pragma unroll
    for (int kh = 0; kh < 2; ++kh)
#pragma unroll
      for (int mf = 0; mf < 4; ++mf)
#pragma unroll
        for (int nf = 0; nf < 4; ++nf)
          acc[mf][nf] = __builtin_amdgcn_mfma_f32_16x16x32_bf16(
              a[mf][kh], b[nf][kh], acc[mf][nf], 0, 0, 0);
    __builtin_amdgcn_s_setprio(0);
    __syncthreads();   // drains vmcnt(0): stage(t+1) complete; buf flip safe
  }

  // ---- epilogue ----
  if constexpr (MODE == 0) {
    u16* C = (sec == 0) ? Cq : (sec == 1) ? Ck : Cv;
#pragma unroll
    for (int mf = 0; mf < 4; ++mf)
#pragma unroll
      for (int nf = 0; nf < 4; ++nf)
#pragma unroll
        for (int r = 0; r < 4; ++r) {
          const int mloc = (m0 & 8191) + wm * 64 + mf * 16 + qr * 4 + r;
          const int n = n0 + wn * 64 + nf * 16 + cl;
          const int bb = mloc >> 11, s = mloc & (S_LEN - 1);
          const int h = n >> 6, d = n & (DHEAD - 1);
          const size_t idx =
              (sec < 2) ? (((size_t)bb * NHEADS + h) * S_LEN + s) * DHEAD + d
                        : (((size_t)bb * NHEADS + h) * DHEAD + d) * S_LEN + s;
          C[idx] = f32_bf16(acc[mf][nf][r]);
        }
  } else {
#pragma unroll
    for (int mf = 0; mf < 4; ++mf)
#pragma unroll
      for (int nf = 0; nf < 4; ++nf)
#pragma unroll
        for (int r = 0; r < 4; ++r) {
          const int m = m0 + wm * 64 + mf * 16 + qr * 4 + r;
          const int n = n0 + wn * 64 + nf * 16 + cl;
          Cf[(size_t)m * 1024 + n] = acc[mf][nf][r];
        }
  }
}

// Causal flash attention, no-max softmax. Qp/Kp: [B,H,S,D]; VpT: [B,H,D,S].
// 512 blocks; block = (column, pair): q-tile (15-pair) then (pair) ->
// exactly 34 K-iterations per block (perfect causal load balance).
// QUAD-buffered K/V (2 groups x 2 tiles, 80KB LDS -> 2 blocks/CU): ONE
// barrier per TWO 64-key tiles -- halves the drain/skew events, and the
// stage->drain distance is two full compute bodies. nkt = 2qt+2 is always
// even, so groups have no tail. XCD-swizzled (8 columns per XCD).
__global__ __launch_bounds__(256, 2) void attn_causal(
    const u16* __restrict__ Qp, const u16* __restrict__ Kp,
    const u16* __restrict__ VpT, u16* __restrict__ Out) {
  __shared__ __align__(16) u16 lK[2][2][64 * 64];  // [grp parity][slot]
  __shared__ __align__(16) u16 lV[2][2][64 * 64];  // chunk(d,kc)=d*8+(kc^(d&7))
  __shared__ __align__(16) u16 pb[4][32 * 64];     // per-wave P
  const int t = threadIdx.x;
  const int lane = t & 63, w = t >> 6;
  const int qr = lane >> 4, cl = lane & 15;
  // id = xcd + 8*(pair + 8*colgroup): all 8 pairs of 8 columns share an XCD
  const int id = blockIdx.x;
  const int col = (id & 7) + ((id >> 6) << 3);   // 0..63 = h + 16*b
  const int pair = (id >> 3) & 7;
  const int h = col & 15, b = col >> 4;
  const size_t bh = ((size_t)b * NHEADS + h) * S_LEN * DHEAD;
  const u16* Qb = Qp + bh;
  const u16* Kb = Kp + bh;
  const u16* Vb = VpT + bh;   // [d][s], row stride S_LEN

  v8s vone;
#pragma unroll
  for (int j = 0; j < 8; ++j) vone[j] = (short)0x3F80;   // bf16 1.0
  const float SC = 0.125f * 1.4426950408889634f;         // (1/8)*log2(e)

  // stage 64-key tile TILE of K and V into (GP, SL)
#define STAGE_T(TILE, GP, SL)                                                 \
  do {                                                                        \
    const int kn_ = (TILE) << 6;                                              \
    _Pragma("unroll") for (int i_ = 0; i_ < 2; ++i_) {                        \
      const int c_ = t + (i_ << 8);                                           \
      const int krow_ = c_ >> 3, kdc_ = (c_ & 7) ^ (krow_ & 7);               \
      async16(Kb + (size_t)(kn_ + krow_) * DHEAD + kdc_ * 8,                  \
              &lK[GP][SL][(w * 64 + (i_ << 8)) * 8]);                         \
      const int vd_ = c_ >> 3, vkc_ = (c_ & 7) ^ (vd_ & 7);                   \
      async16(Vb + (size_t)vd_ * S_LEN + kn_ + vkc_ * 8,                      \
              &lV[GP][SL][(w * 64 + (i_ << 8)) * 8]);                         \
    }                                                                         \
  } while (0)

  for (int phase = 0; phase < 2; ++phase) {
    const int qt = phase == 0 ? (15 - pair) : pair;   // heavy tile first
    const int q0 = qt << 7;
    const int wr0 = q0 + w * 32;   // this wave's first q-row

    v8s aq[2][2];
#pragma unroll
    for (int mf = 0; mf < 2; ++mf)
#pragma unroll
      for (int kf = 0; kf < 2; ++kf)
        aq[mf][kf] = *(const v8s*)(Qb + (size_t)(wr0 + mf * 16 + cl) * DHEAD +
                                   kf * 32 + qr * 8);

    v4f o[2][4], lac[2];
#pragma unroll
    for (int mf = 0; mf < 2; ++mf) {
      lac[mf] = (v4f){0.f, 0.f, 0.f, 0.f};
#pragma unroll
      for (int nf = 0; nf < 4; ++nf) o[mf][nf] = (v4f){0.f, 0.f, 0.f, 0.f};
    }

    const int ngrp = qt + 1;          // nkt = 2*qt+2 tiles = ngrp groups of 2
    __syncthreads();   // prior phase's LDS reads complete before re-staging
    STAGE_T(0, 0, 0);
    STAGE_T(1, 0, 1);

    for (int g = 0; g < ngrp; ++g) {
      const int gp = g & 1;
      __syncthreads();   // group g's 8 loads landed; buf[1-gp] free
      if (g + 1 < ngrp) {
        STAGE_T(2 * g + 2, 1 - gp, 0);
        STAGE_T(2 * g + 3, 1 - gp, 1);
      }
#pragma unroll
      for (int sl = 0; sl < 2; ++sl) {
        const int kt = 2 * g + sl;
        const int k0 = kt << 6;
        if (k0 > wr0 + 31) continue;   // wave-uniform: fully above diagonal
        const u16* lKc = &lK[gp][sl][0];
        const u16* lVc = &lV[gp][sl][0];

        // ---- S = Q K^T  (16 MFMA) ----
        v4f sacc[2][4];
#pragma unroll
        for (int mf = 0; mf < 2; ++mf)
#pragma unroll
          for (int ni = 0; ni < 4; ++ni) sacc[mf][ni] = (v4f){0.f, 0.f, 0.f, 0.f};
#pragma unroll
        for (int kf = 0; kf < 2; ++kf)
#pragma unroll
          for (int ni = 0; ni < 4; ++ni) {
            const v8s bk = *(const v8s*)&lKc[((ni * 16 + cl) * 8 +
                                             (((kf << 2) + qr) ^ (cl & 7))) * 8];
            sacc[0][ni] = __builtin_amdgcn_mfma_f32_16x16x32_bf16(
                aq[0][kf], bk, sacc[0][ni], 0, 0, 0);
            sacc[1][ni] = __builtin_amdgcn_mfma_f32_16x16x32_bf16(
                aq[1][kf], bk, sacc[1][ni], 0, 0, 0);
          }

        // ---- exp2, (diagonal-only) mask, truncate-to-bf16, store P ----
#pragma unroll
        for (int mf = 0; mf < 2; ++mf) {
          const int rowb0 = wr0 + mf * 16;
          if (k0 + 63 <= rowb0) {        // wave-uniform: no masking here
#pragma unroll
            for (int ni = 0; ni < 4; ++ni) {
              const int kc = ni * 2 + (cl >> 3);
#pragma unroll
              for (int r = 0; r < 4; ++r) {
                const float e = EXP2F(sacc[mf][ni][r] * SC);
                pb[w][((kc * 32 + mf * 16 + r * 4 + qr) << 3) + (cl & 7)] =
                    (u16)(__float_as_uint(e) >> 16);
              }
            }
          } else {                        // diagonal: mask then exp
            const int rowb = rowb0 + qr * 4;
#pragma unroll
            for (int ni = 0; ni < 4; ++ni) {
              const int colk = k0 + ni * 16 + cl;
              const int kc = ni * 2 + (cl >> 3);
#pragma unroll
              for (int r = 0; r < 4; ++r) {
                float e = EXP2F(sacc[mf][ni][r] * SC);
                if (colk > rowb + r) e = 0.f;
                pb[w][((kc * 32 + mf * 16 + r * 4 + qr) << 3) + (cl & 7)] =
                    (u16)(__float_as_uint(e) >> 16);
              }
            }
          }
        }

        // ---- O += P V, l += P 1  (wave-local pb: lgkmcnt ordering only) ----
#pragma unroll
        for (int kf = 0; kf < 2; ++kf) {
          const int kc = (kf << 2) + qr;
          const int sig0 = ((cl & 3) << 2) + (cl >> 2);
          const v8s ap0 = *(const v8s*)&pb[w][((kc * 32 + sig0) << 3)];
          const v8s ap1 = *(const v8s*)&pb[w][((kc * 32 + 16 + sig0) << 3)];
          lac[0] = __builtin_amdgcn_mfma_f32_16x16x32_bf16(ap0, vone, lac[0], 0, 0, 0);
          lac[1] = __builtin_amdgcn_mfma_f32_16x16x32_bf16(ap1, vone, lac[1], 0, 0, 0);
#pragma unroll
          for (int nf = 0; nf < 4; ++nf) {
            const v8s bv = *(const v8s*)&lVc[((nf * 16 + cl) * 8 +
                                             (kc ^ (cl & 7))) * 8];
            o[0][nf] = __builtin_amdgcn_mfma_f32_16x16x32_bf16(ap0, bv, o[0][nf], 0, 0, 0);
            o[1][nf] = __builtin_amdgcn_mfma_f32_16x16x32_bf16(ap1, bv, o[1][nf], 0, 0, 0);
          }
        }
      }
    }

    // epilogue: O / l
#pragma unroll
    for (int mf = 0; mf < 2; ++mf) {
      float inv[4];
#pragma unroll
      for (int r = 0; r < 4; ++r) inv[r] = 1.0f / lac[mf][r];
#pragma unroll
      for (int nf = 0; nf < 4; ++nf)
#pragma unroll
        for (int r = 0; r < 4; ++r) {
          const int row = wr0 + mf * 16 + qr * 4 + r;
          const int colo = h * DHEAD + nf * 16 + cl;
          Out[((size_t)b * S_LEN + row) * EMB + colo] = f32_bf16(o[mf][nf][r] * inv[r]);
        }
    }
  }
#undef STAGE_T
}

extern "C" void kernel_launch(void* const* d_in, const int* in_sizes, int n_in,
                              void* d_out, int out_size, void* d_ws, size_t ws_size,
                              hipStream_t stream) {
  (void)in_sizes; (void)n_in; (void)out_size; (void)ws_size;
  const float* q  = (const float*)d_in[0];
  const float* k  = (const float*)d_in[1];
  const float* v  = (const float*)d_in[2];
  // d_in[3] = causal mask (int32) — implemented analytically, not read
  const float* wq = (const float*)d_in[4];
  const float* wk = (const float*)d_in[5];
  const float* wv = (const float*)d_in[6];
  const float* wo = (const float*)d_in[7];
  float* out = (float*)d_out;   // reference output dtype is float32

  const size_t MT = (size_t)4 * S_LEN * EMB;   // 8,388,608 elems
  const size_t WT = (size_t)EMB * EMB;         // 1,048,576 elems
  u16* p = (u16*)d_ws;
  u16* xq = p; p += MT;     // xq|xk|xv contiguous: A-matrix of the fused QKV GEMM
  u16* xk = p; p += MT;
  u16* xv = p; p += MT;
  u16* wqb = p; p += WT;
  u16* wkb = p; p += WT;
  u16* wvb = p; p += WT;
  u16* wob = p; p += WT;
  u16* Qp = p; p += MT;
  u16* Kp = p; p += MT;
  u16* Vp = p; p += MT;
  u16* Ao = xq;          // xq dead after projection GEMM — reuse

  const dim3 blk(256);
  hipLaunchKernelGGL(cvt_all, dim3(512, 7), blk, 0, stream,
                     (const float4*)q, (const float4*)k, (const float4*)v,
                     (const float4*)wq, (const float4*)wk, (const float4*)wv,
                     (const float4*)wo,
                     (ushort4*)xq, (ushort4*)xk, (ushort4*)xv,
                     (ushort4*)wqb, (ushort4*)wkb, (ushort4*)wvb, (ushort4*)wob,
                     (int)(MT / 4), (int)(WT / 4));
  // 192 m-tiles x 8 n-tiles = 1536 blocks; 2 blocks/CU -> 3 rounds
  hipLaunchKernelGGL((gemm2ph<0>), dim3(1536), blk, 0, stream,
                     xq, wqb, wkb, wvb, Qp, Kp, Vp, (float*)nullptr, 192);
  hipLaunchKernelGGL(attn_causal, dim3(512), blk, 0, stream, Qp, Kp, Vp, Ao);
  // 64 m-tiles x 8 n-tiles = 512 blocks; 2 blocks/CU -> 1 round
  hipLaunchKernelGGL((gemm2ph<1>), dim3(512), blk, 0, stream,
                     Ao, wob, (const u16*)nullptr, (const u16*)nullptr,
                     (u16*)nullptr, (u16*)nullptr, (u16*)nullptr, out, 64);
}

// Round 5
// 340.712 us; speedup vs baseline: 1.0647x; 1.0257x over previous
//
#include <hip/hip_runtime.h>

typedef unsigned short u16;
typedef __attribute__((ext_vector_type(8))) short v8s;   // 8 x bf16 (4 VGPRs)
typedef __attribute__((ext_vector_type(4))) float v4f;   // MFMA 16x16 accumulator

#define S_LEN  2048
#define NHEADS 16
#define DHEAD  64
#define EMB    1024

#if __has_builtin(__builtin_amdgcn_exp2f)
#define EXP2F __builtin_amdgcn_exp2f
#else
#define EXP2F exp2f
#endif

__device__ __forceinline__ u16 f32_bf16(float f) {
  union { float f; unsigned u; } x; x.f = f;
  unsigned r = x.u + 0x7fffu + ((x.u >> 16) & 1u);   // RNE
  return (u16)(r >> 16);
}

__device__ __forceinline__ void async16(const void* g, void* l) {
  // global -> LDS direct DMA, 16B per lane; LDS dest = wave-uniform base + lane*16
  __builtin_amdgcn_global_load_lds(
      (const __attribute__((address_space(1))) unsigned int*)g,
      (__attribute__((address_space(3))) unsigned int*)l, 16, 0, 0);
}

// ---- fp32 -> bf16 conversion, all 7 tensors in one launch ----
__global__ __launch_bounds__(256) void cvt_all(
    const float4* __restrict__ s0, const float4* __restrict__ s1,
    const float4* __restrict__ s2, const float4* __restrict__ s3,
    const float4* __restrict__ s4, const float4* __restrict__ s5,
    const float4* __restrict__ s6,
    ushort4* __restrict__ d0, ushort4* __restrict__ d1,
    ushort4* __restrict__ d2, ushort4* __restrict__ d3,
    ushort4* __restrict__ d4, ushort4* __restrict__ d5,
    ushort4* __restrict__ d6, int nbig, int nsmall) {
  const int y = blockIdx.y;
  const float4* s; ushort4* d;
  switch (y) {
    case 0: s = s0; d = d0; break;  case 1: s = s1; d = d1; break;
    case 2: s = s2; d = d2; break;  case 3: s = s3; d = d3; break;
    case 4: s = s4; d = d4; break;  case 5: s = s5; d = d5; break;
    default: s = s6; d = d6; break;
  }
  const int n4 = (y < 3) ? nbig : nsmall;
  for (int i = blockIdx.x * 256 + threadIdx.x; i < n4; i += gridDim.x * 256) {
    const float4 v = s[i];
    ushort4 o;
    o.x = f32_bf16(v.x); o.y = f32_bf16(v.y);
    o.z = f32_bf16(v.z); o.w = f32_bf16(v.w);
    d[i] = o;
  }
}

// ============================================================================
// 128x128 tile, BK=64, **512 threads / 8 waves** (2Mx4N, 64x32 per wave),
// 64 KiB LDS -> 2 blocks/CU = 16 waves/CU = 4 waves/SIMD (2x round-2 TLP).
// 2-phase K-loop (round-2 structure, best measured 88.7us): stage(t+1) issued
// at TOP of the body, single __syncthreads() at bottom.
// T2 XOR-swizzle on 16B chunks within each 128B row (verified 0 conflicts).
// Round-2 block mapping (best measured): XCD-residue x owns n-panel x ->
// W panel (256KB) permanently L2-resident; 50% of staging guaranteed L2-hot.
//
// MODE 0: fused QKV projection. A=[xq;xk;xv] [24576,1024]; sec=m0>>13 picks
//         W and output (Cq/Ck: [B,H,S,D] bf16; Cv: [B,H,D,S] bf16).
// MODE 1: output projection, C fp32 row-major [M,1024].
// ============================================================================
template <int MODE>
__global__ __launch_bounds__(512, 2) void gemm2ph(
    const u16* __restrict__ A, const u16* __restrict__ W0,
    const u16* __restrict__ W1, const u16* __restrict__ W2,
    u16* __restrict__ Cq, u16* __restrict__ Ck, u16* __restrict__ Cv,
    float* __restrict__ Cf, int mtiles) {
  const int K = 1024;
  const int NKT = 16;                          // K / 64
  __shared__ __align__(16) u16 lA[2][128 * 64];   // 2 x 16 KB
  __shared__ __align__(16) u16 lB[2][128 * 64];   // total 64 KiB
  const int t = threadIdx.x;
  const int lane = t & 63, wv = t >> 6;
  const int wm = wv >> 2, wn = wv & 3;         // 2M x 4N waves, 64x32/wave
  const int qr = lane >> 4, cl = lane & 15;

  // Round-2 mapping: sid = xcd-residue * (nwg/8) + bid/8; bn = sid / mtiles
  // (each XCD-residue owns exactly one n-panel since nwg/8 == mtiles here)
  const int nwg = gridDim.x;
  const int sid = (blockIdx.x & 7) * (nwg >> 3) + (blockIdx.x >> 3);
  const int bm = sid % mtiles, bn = sid / mtiles;
  const int m0 = bm << 7, n0 = bn << 7;
  const int sec = (MODE == 0) ? (m0 >> 13) : 0;
  const u16* W =
      (MODE == 0) ? ((sec == 0) ? W0 : (sec == 1) ? W1 : W2) : W0;

  v4f acc[4][2];
#pragma unroll
  for (int i = 0; i < 4; ++i)
#pragma unroll
    for (int j = 0; j < 2; ++j) acc[i][j] = (v4f){0.f, 0.f, 0.f, 0.f};

  // Per-thread staging source: c = t + u*512 -> row = (t>>3) + u*64 (64%8==0
  // so the chunk swizzle is constant across u), chunk = (t&7) ^ (row&7).
  const int srow = t >> 3;
  const int sw = ((t & 7) ^ (srow & 7)) << 3;   // u16 offset within the row
  const u16* aS[2];
  const u16* bS[2];
#pragma unroll
  for (int u = 0; u < 2; ++u) {
    aS[u] = A + (size_t)(m0 + srow + u * 64) * K + sw;
    bS[u] = W + (size_t)(n0 + srow + u * 64) * K + sw;
  }

  // prologue: stage tile 0 into buf 0
#pragma unroll
  for (int u = 0; u < 2; ++u) async16(aS[u], &lA[0][(t + (u << 9)) << 3]);
#pragma unroll
  for (int u = 0; u < 2; ++u) async16(bS[u], &lB[0][(t + (u << 9)) << 3]);
  __syncthreads();

  for (int kt = 0; kt < NKT; ++kt) {
    const int cur = kt & 1;
    if (kt + 1 < NKT) {                         // stage(t+1) FIRST
      const int off = (kt + 1) << 6;
#pragma unroll
      for (int u = 0; u < 2; ++u)
        async16(aS[u] + off, &lA[1 - cur][(t + (u << 9)) << 3]);
#pragma unroll
      for (int u = 0; u < 2; ++u)
        async16(bS[u] + off, &lB[1 - cur][(t + (u << 9)) << 3]);
    }
    v8s a[4][2], b[2][2];
#pragma unroll
    for (int mf = 0; mf < 4; ++mf)
#pragma unroll
      for (int kh = 0; kh < 2; ++kh) {
        const int R = wm * 64 + mf * 16 + cl;
        a[mf][kh] =
            *(const v8s*)&lA[cur][R * 64 + ((((kh << 2) + qr) ^ (R & 7)) << 3)];
      }
#pragma unroll
    for (int nf = 0; nf < 2; ++nf)
#pragma unroll
      for (int kh = 0; kh < 2; ++kh) {
        const int R = wn * 32 + nf * 16 + cl;
        b[nf][kh] =
            *(const v8s*)&lB[cur][R * 64 + ((((kh << 2) + qr) ^ (R & 7)) << 3)];
      }
    __builtin_amdgcn_s_setprio(1);
#pragma unroll
    for (int kh = 0; kh < 2; ++kh)
#pragma unroll
      for (int mf = 0; mf < 4; ++mf)
#pragma unroll
        for (int nf = 0; nf < 2; ++nf)
          acc[mf][nf] = __builtin_amdgcn_mfma_f32_16x16x32_bf16(
              a[mf][kh], b[nf][kh], acc[mf][nf], 0, 0, 0);
    __builtin_amdgcn_s_setprio(0);
    __syncthreads();   // drains vmcnt(0): stage(t+1) complete; buf flip safe
  }

  // ---- epilogue ----
  if constexpr (MODE == 0) {
    u16* C = (sec == 0) ? Cq : (sec == 1) ? Ck : Cv;
#pragma unroll
    for (int mf = 0; mf < 4; ++mf)
#pragma unroll
      for (int nf = 0; nf < 2; ++nf)
#pragma unroll
        for (int r = 0; r < 4; ++r) {
          const int mloc = (m0 & 8191) + wm * 64 + mf * 16 + qr * 4 + r;
          const int n = n0 + wn * 32 + nf * 16 + cl;
          const int bb = mloc >> 11, s = mloc & (S_LEN - 1);
          const int h = n >> 6, d = n & (DHEAD - 1);
          const size_t idx =
              (sec < 2) ? (((size_t)bb * NHEADS + h) * S_LEN + s) * DHEAD + d
                        : (((size_t)bb * NHEADS + h) * DHEAD + d) * S_LEN + s;
          C[idx] = f32_bf16(acc[mf][nf][r]);
        }
  } else {
#pragma unroll
    for (int mf = 0; mf < 4; ++mf)
#pragma unroll
      for (int nf = 0; nf < 2; ++nf)
#pragma unroll
        for (int r = 0; r < 4; ++r) {
          const int m = m0 + wm * 64 + mf * 16 + qr * 4 + r;
          const int n = n0 + wn * 32 + nf * 16 + cl;
          Cf[(size_t)m * 1024 + n] = acc[mf][nf][r];
        }
  }
}

// Causal flash attention, no-max softmax. Qp/Kp: [B,H,S,D]; VpT: [B,H,D,S].
// 512 blocks; block = (column, pair): q-tile (15-pair) then (pair) ->
// exactly 34 K-iterations per block (perfect causal load balance).
// QUAD-buffered K/V (2 groups x 2 tiles, 80KB LDS -> 2 blocks/CU): ONE
// barrier per TWO 64-key tiles (verified ~10us win, round 4).
__global__ __launch_bounds__(256, 2) void attn_causal(
    const u16* __restrict__ Qp, const u16* __restrict__ Kp,
    const u16* __restrict__ VpT, u16* __restrict__ Out) {
  __shared__ __align__(16) u16 lK[2][2][64 * 64];  // [grp parity][slot]
  __shared__ __align__(16) u16 lV[2][2][64 * 64];  // chunk(d,kc)=d*8+(kc^(d&7))
  __shared__ __align__(16) u16 pb[4][32 * 64];     // per-wave P
  const int t = threadIdx.x;
  const int lane = t & 63, w = t >> 6;
  const int qr = lane >> 4, cl = lane & 15;
  // id = xcd + 8*(pair + 8*colgroup): all 8 pairs of 8 columns share an XCD
  const int id = blockIdx.x;
  const int col = (id & 7) + ((id >> 6) << 3);   // 0..63 = h + 16*b
  const int pair = (id >> 3) & 7;
  const int h = col & 15, b = col >> 4;
  const size_t bh = ((size_t)b * NHEADS + h) * S_LEN * DHEAD;
  const u16* Qb = Qp + bh;
  const u16* Kb = Kp + bh;
  const u16* Vb = VpT + bh;   // [d][s], row stride S_LEN

  v8s vone;
#pragma unroll
  for (int j = 0; j < 8; ++j) vone[j] = (short)0x3F80;   // bf16 1.0
  const float SC = 0.125f * 1.4426950408889634f;         // (1/8)*log2(e)

  // stage 64-key tile TILE of K and V into (GP, SL)
#define STAGE_T(TILE, GP, SL)                                                 \
  do {                                                                        \
    const int kn_ = (TILE) << 6;                                              \
    _Pragma("unroll") for (int i_ = 0; i_ < 2; ++i_) {                        \
      const int c_ = t + (i_ << 8);                                           \
      const int krow_ = c_ >> 3, kdc_ = (c_ & 7) ^ (krow_ & 7);               \
      async16(Kb + (size_t)(kn_ + krow_) * DHEAD + kdc_ * 8,                  \
              &lK[GP][SL][(w * 64 + (i_ << 8)) * 8]);                         \
      const int vd_ = c_ >> 3, vkc_ = (c_ & 7) ^ (vd_ & 7);                   \
      async16(Vb + (size_t)vd_ * S_LEN + kn_ + vkc_ * 8,                      \
              &lV[GP][SL][(w * 64 + (i_ << 8)) * 8]);                         \
    }                                                                         \
  } while (0)

  for (int phase = 0; phase < 2; ++phase) {
    const int qt = phase == 0 ? (15 - pair) : pair;   // heavy tile first
    const int q0 = qt << 7;
    const int wr0 = q0 + w * 32;   // this wave's first q-row

    v8s aq[2][2];
#pragma unroll
    for (int mf = 0; mf < 2; ++mf)
#pragma unroll
      for (int kf = 0; kf < 2; ++kf)
        aq[mf][kf] = *(const v8s*)(Qb + (size_t)(wr0 + mf * 16 + cl) * DHEAD +
                                   kf * 32 + qr * 8);

    v4f o[2][4], lac[2];
#pragma unroll
    for (int mf = 0; mf < 2; ++mf) {
      lac[mf] = (v4f){0.f, 0.f, 0.f, 0.f};
#pragma unroll
      for (int nf = 0; nf < 4; ++nf) o[mf][nf] = (v4f){0.f, 0.f, 0.f, 0.f};
    }

    const int ngrp = qt + 1;          // nkt = 2*qt+2 tiles = ngrp groups of 2
    __syncthreads();   // prior phase's LDS reads complete before re-staging
    STAGE_T(0, 0, 0);
    STAGE_T(1, 0, 1);

    for (int g = 0; g < ngrp; ++g) {
      const int gp = g & 1;
      __syncthreads();   // group g's 8 loads landed; buf[1-gp] free
      if (g + 1 < ngrp) {
        STAGE_T(2 * g + 2, 1 - gp, 0);
        STAGE_T(2 * g + 3, 1 - gp, 1);
      }
#pragma unroll
      for (int sl = 0; sl < 2; ++sl) {
        const int kt = 2 * g + sl;
        const int k0 = kt << 6;
        if (k0 > wr0 + 31) continue;   // wave-uniform: fully above diagonal
        const u16* lKc = &lK[gp][sl][0];
        const u16* lVc = &lV[gp][sl][0];

        // ---- S = Q K^T  (16 MFMA) ----
        v4f sacc[2][4];
#pragma unroll
        for (int mf = 0; mf < 2; ++mf)
#pragma unroll
          for (int ni = 0; ni < 4; ++ni) sacc[mf][ni] = (v4f){0.f, 0.f, 0.f, 0.f};
#pragma unroll
        for (int kf = 0; kf < 2; ++kf)
#pragma unroll
          for (int ni = 0; ni < 4; ++ni) {
            const v8s bk = *(const v8s*)&lKc[((ni * 16 + cl) * 8 +
                                             (((kf << 2) + qr) ^ (cl & 7))) * 8];
            sacc[0][ni] = __builtin_amdgcn_mfma_f32_16x16x32_bf16(
                aq[0][kf], bk, sacc[0][ni], 0, 0, 0);
            sacc[1][ni] = __builtin_amdgcn_mfma_f32_16x16x32_bf16(
                aq[1][kf], bk, sacc[1][ni], 0, 0, 0);
          }

        // ---- exp2, (diagonal-only) mask, truncate-to-bf16, store P ----
#pragma unroll
        for (int mf = 0; mf < 2; ++mf) {
          const int rowb0 = wr0 + mf * 16;
          if (k0 + 63 <= rowb0) {        // wave-uniform: no masking here
#pragma unroll
            for (int ni = 0; ni < 4; ++ni) {
              const int kc = ni * 2 + (cl >> 3);
#pragma unroll
              for (int r = 0; r < 4; ++r) {
                const float e = EXP2F(sacc[mf][ni][r] * SC);
                pb[w][((kc * 32 + mf * 16 + r * 4 + qr) << 3) + (cl & 7)] =
                    (u16)(__float_as_uint(e) >> 16);
              }
            }
          } else {                        // diagonal: mask then exp
            const int rowb = rowb0 + qr * 4;
#pragma unroll
            for (int ni = 0; ni < 4; ++ni) {
              const int colk = k0 + ni * 16 + cl;
              const int kc = ni * 2 + (cl >> 3);
#pragma unroll
              for (int r = 0; r < 4; ++r) {
                float e = EXP2F(sacc[mf][ni][r] * SC);
                if (colk > rowb + r) e = 0.f;
                pb[w][((kc * 32 + mf * 16 + r * 4 + qr) << 3) + (cl & 7)] =
                    (u16)(__float_as_uint(e) >> 16);
              }
            }
          }
        }

        // ---- O += P V, l += P 1  (wave-local pb: lgkmcnt ordering only) ----
#pragma unroll
        for (int kf = 0; kf < 2; ++kf) {
          const int kc = (kf << 2) + qr;
          const int sig0 = ((cl & 3) << 2) + (cl >> 2);
          const v8s ap0 = *(const v8s*)&pb[w][((kc * 32 + sig0) << 3)];
          const v8s ap1 = *(const v8s*)&pb[w][((kc * 32 + 16 + sig0) << 3)];
          lac[0] = __builtin_amdgcn_mfma_f32_16x16x32_bf16(ap0, vone, lac[0], 0, 0, 0);
          lac[1] = __builtin_amdgcn_mfma_f32_16x16x32_bf16(ap1, vone, lac[1], 0, 0, 0);
#pragma unroll
          for (int nf = 0; nf < 4; ++nf) {
            const v8s bv = *(const v8s*)&lVc[((nf * 16 + cl) * 8 +
                                             (kc ^ (cl & 7))) * 8];
            o[0][nf] = __builtin_amdgcn_mfma_f32_16x16x32_bf16(ap0, bv, o[0][nf], 0, 0, 0);
            o[1][nf] = __builtin_amdgcn_mfma_f32_16x16x32_bf16(ap1, bv, o[1][nf], 0, 0, 0);
          }
        }
      }
    }

    // epilogue: O / l
#pragma unroll
    for (int mf = 0; mf < 2; ++mf) {
      float inv[4];
#pragma unroll
      for (int r = 0; r < 4; ++r) inv[r] = 1.0f / lac[mf][r];
#pragma unroll
      for (int nf = 0; nf < 4; ++nf)
#pragma unroll
        for (int r = 0; r < 4; ++r) {
          const int row = wr0 + mf * 16 + qr * 4 + r;
          const int colo = h * DHEAD + nf * 16 + cl;
          Out[((size_t)b * S_LEN + row) * EMB + colo] = f32_bf16(o[mf][nf][r] * inv[r]);
        }
    }
  }
#undef STAGE_T
}

extern "C" void kernel_launch(void* const* d_in, const int* in_sizes, int n_in,
                              void* d_out, int out_size, void* d_ws, size_t ws_size,
                              hipStream_t stream) {
  (void)in_sizes; (void)n_in; (void)out_size; (void)ws_size;
  const float* q  = (const float*)d_in[0];
  const float* k  = (const float*)d_in[1];
  const float* v  = (const float*)d_in[2];
  // d_in[3] = causal mask (int32) — implemented analytically, not read
  const float* wq = (const float*)d_in[4];
  const float* wk = (const float*)d_in[5];
  const float* wv = (const float*)d_in[6];
  const float* wo = (const float*)d_in[7];
  float* out = (float*)d_out;   // reference output dtype is float32

  const size_t MT = (size_t)4 * S_LEN * EMB;   // 8,388,608 elems
  const size_t WT = (size_t)EMB * EMB;         // 1,048,576 elems
  u16* p = (u16*)d_ws;
  u16* xq = p; p += MT;     // xq|xk|xv contiguous: A-matrix of the fused QKV GEMM
  u16* xk = p; p += MT;
  u16* xv = p; p += MT;
  u16* wqb = p; p += WT;
  u16* wkb = p; p += WT;
  u16* wvb = p; p += WT;
  u16* wob = p; p += WT;
  u16* Qp = p; p += MT;
  u16* Kp = p; p += MT;
  u16* Vp = p; p += MT;
  u16* Ao = xq;          // xq dead after projection GEMM — reuse

  const dim3 blk(256);
  hipLaunchKernelGGL(cvt_all, dim3(512, 7), blk, 0, stream,
                     (const float4*)q, (const float4*)k, (const float4*)v,
                     (const float4*)wq, (const float4*)wk, (const float4*)wv,
                     (const float4*)wo,
                     (ushort4*)xq, (ushort4*)xk, (ushort4*)xv,
                     (ushort4*)wqb, (ushort4*)wkb, (ushort4*)wvb, (ushort4*)wob,
                     (int)(MT / 4), (int)(WT / 4));
  // 192 m-tiles x 8 n-tiles = 1536 blocks; 512 thr, 2 blocks/CU -> 3 rounds
  hipLaunchKernelGGL((gemm2ph<0>), dim3(1536), dim3(512), 0, stream,
                     xq, wqb, wkb, wvb, Qp, Kp, Vp, (float*)nullptr, 192);
  hipLaunchKernelGGL(attn_causal, dim3(512), blk, 0, stream, Qp, Kp, Vp, Ao);
  // 64 m-tiles x 8 n-tiles = 512 blocks; 512 thr, 2 blocks/CU -> 1 round
  hipLaunchKernelGGL((gemm2ph<1>), dim3(512), dim3(512), 0, stream,
                     Ao, wob, (const u16*)nullptr, (const u16*)nullptr,
                     (u16*)nullptr, (u16*)nullptr, (u16*)nullptr, out, 64);
}